// Round 14
// baseline (6496.577 us; speedup 1.0000x reference)
//
#include <hip/hip_runtime.h>
#include <hip/hip_bf16.h>

// LSTM: B=64, T=512, V=32000, E=256, H=512, O=1
// R14: fragment-direct exchange. No poll phase, no h_lds, no B1: each MFMA
// lane loads its OWN A-fragment (4 tagged u64 = 8 h bf16 for its batch row)
// straight from the tagged global buffer, validating tags in-registers and
// retrying (sc0/agent alternating) only on miss. Groups of 4 kt are issued
// one group ahead so load flight hides under the previous group's MFMAs.
// Geometry: 4 domains x 16 batches (FULL 16-row A-tiles, no dead rows)
// x 8 blocks (256 gate-cols each), chunked mapping (domain = blockIdx>>3).
// Producers publish tagged pairs dual (sc0 + agent); liveness placement-free.
#define TB 512
#define NB 64
#define EE 256
#define HH 512
#define ND 4           // sync domains
#define DB 16          // batches per domain (= full A-tile)
#define NBLK 8         // blocks per domain
#define NT 256         // threads per block (4 waves)
#define NCOLP 260      // P_lds padded row (floats)
#define NPAIR 256      // h pairs per batch
#define GCOLS 2048
#define SLOWOFF ((size_t)0x40000)  // slow buffer offset (fast at 0, 256KB each)
#define XGOFF   ((size_t)1 << 20)  // xg offset in d_ws

typedef __bf16 bf16_t;
typedef bf16_t bf16x8 __attribute__((ext_vector_type(8)));
typedef float  f32x4  __attribute__((ext_vector_type(4)));
typedef unsigned u32;
typedef unsigned long long u64;
typedef u32 u32x4 __attribute__((ext_vector_type(4)));

__device__ __forceinline__ float sigf(float x) { return 1.0f / (1.0f + __expf(-x)); }
__device__ __forceinline__ float tanhfast(float x) {
    float xc = fminf(fmaxf(x, -15.0f), 15.0f);
    float e  = __expf(2.0f * xc);
    return (e - 1.0f) / (e + 1.0f);
}
__device__ __forceinline__ u32 bfbits(float f) {
    bf16_t h = (bf16_t)f;
    return (u32)__builtin_bit_cast(unsigned short, h);
}
__device__ __forceinline__ bf16x8 cvt8(float4 a, float4 b) {
    bf16x8 v;
    v[0]=(bf16_t)a.x; v[1]=(bf16_t)a.y; v[2]=(bf16_t)a.z; v[3]=(bf16_t)a.w;
    v[4]=(bf16_t)b.x; v[5]=(bf16_t)b.y; v[6]=(bf16_t)b.z; v[7]=(bf16_t)b.w;
    return v;
}
__device__ __forceinline__ f32x4 cvtxg(u64 v) {
    f32x4 r;
    r[0] = __uint_as_float((u32)( v        & 0xFFFFu) << 16);
    r[1] = __uint_as_float((u32)((v >> 16) & 0xFFFFu) << 16);
    r[2] = __uint_as_float((u32)((v >> 32) & 0xFFFFu) << 16);
    r[3] = __uint_as_float((u32)((v >> 48) & 0xFFFFu) << 16);
    return r;
}

// LDS-only barrier (lgkmcnt drain + s_barrier): vmem stays in flight.
__device__ __forceinline__ void bar_lds() {
    __builtin_amdgcn_sched_barrier(0);
    asm volatile("s_waitcnt lgkmcnt(0)" ::: "memory");
    __builtin_amdgcn_s_barrier();
    __builtin_amdgcn_sched_barrier(0);
}

// Issue 8 sc0 dwordx4 loads (one 4-kt fragment group) -- NO wait.
__device__ __forceinline__ void frag_issue(u64 fa, u32x4 (&q)[8]) {
    asm volatile(
        "global_load_dwordx4 %0, %8, off sc0\n\t"
        "global_load_dwordx4 %1, %8, off offset:16 sc0\n\t"
        "global_load_dwordx4 %2, %8, off offset:128 sc0\n\t"
        "global_load_dwordx4 %3, %8, off offset:144 sc0\n\t"
        "global_load_dwordx4 %4, %8, off offset:256 sc0\n\t"
        "global_load_dwordx4 %5, %8, off offset:272 sc0\n\t"
        "global_load_dwordx4 %6, %8, off offset:384 sc0\n\t"
        "global_load_dwordx4 %7, %8, off offset:400 sc0"
        : "=&v"(q[0]), "=&v"(q[1]), "=&v"(q[2]), "=&v"(q[3]),
          "=&v"(q[4]), "=&v"(q[5]), "=&v"(q[6]), "=&v"(q[7])
        : "v"(fa)
        : "memory");
}

// Wait for in-flight q, then validate 16 tags. "+v" ties q into the wait asm
// so no use can be scheduled before the waitcnt (rule-18 safety).
__device__ __forceinline__ bool frag_wait_ok(u32x4 (&q)[8], u32 tag) {
    asm volatile("s_waitcnt vmcnt(0)"
        : "+v"(q[0]), "+v"(q[1]), "+v"(q[2]), "+v"(q[3]),
          "+v"(q[4]), "+v"(q[5]), "+v"(q[6]), "+v"(q[7])
        :: "memory");
    __builtin_amdgcn_sched_barrier(0);
    bool ok = true;
    #pragma unroll
    for (int i = 0; i < 8; ++i) ok &= (q[i][1] == tag) & (q[i][3] == tag);
    return ok;
}

// q holds an in-flight sc0 issue for fa; retry (agent / sc0 alternating)
// until all 16 tags match. Liveness: agent rounds see MALL truth.
__device__ __forceinline__ void frag_get(u64 fa, const u64* sb, u32 tag, u32x4 (&q)[8]) {
    int round = 0;
    while (!frag_wait_ok(q, tag)) {
        if ((round++ & 1) == 0) {
            #pragma unroll
            for (int j = 0; j < 4; ++j) {
                u64 h0 = __hip_atomic_load(sb + j*16 + 0, __ATOMIC_RELAXED, __HIP_MEMORY_SCOPE_AGENT);
                u64 h1 = __hip_atomic_load(sb + j*16 + 1, __ATOMIC_RELAXED, __HIP_MEMORY_SCOPE_AGENT);
                u64 h2 = __hip_atomic_load(sb + j*16 + 2, __ATOMIC_RELAXED, __HIP_MEMORY_SCOPE_AGENT);
                u64 h3 = __hip_atomic_load(sb + j*16 + 3, __ATOMIC_RELAXED, __HIP_MEMORY_SCOPE_AGENT);
                q[2*j]   = (u32x4){(u32)h0, (u32)(h0 >> 32), (u32)h1, (u32)(h1 >> 32)};
                q[2*j+1] = (u32x4){(u32)h2, (u32)(h2 >> 32), (u32)h3, (u32)(h3 >> 32)};
            }
        } else {
            frag_issue(fa, q);
        }
    }
}

// ---------------- Phase 1: xg pre-pass GEMM (proven R7, verbatim) ----------------
__global__ __launch_bounds__(256, 1)
void xg_prepass(const int* __restrict__ words, const float* __restrict__ emb,
                const float* __restrict__ Wi, const float* __restrict__ bi,
                const float* __restrict__ bh, bf16_t* __restrict__ xgT)
{
    const int tid = threadIdx.x, lane = tid & 63, wv = tid >> 6;
    const int kgrp = lane >> 4, cl = lane & 15;
    const int cc = blockIdx.x & 7, tc = blockIdx.x >> 3;

    __shared__ __align__(16) bf16_t x_s[64][EE];

    bf16x8 wf[8][4];
    float  bv[4];
    #pragma unroll
    for (int nt = 0; nt < 4; ++nt) {
        int col = cc*256 + wv*64 + nt*16 + cl;
        int wrow = (col & 3)*HH + (col >> 2);
        const float* wr = Wi + (size_t)wrow*EE;
        #pragma unroll
        for (int kt = 0; kt < 8; ++kt) {
            const float4* p = (const float4*)(wr + kt*32 + kgrp*8);
            wf[kt][nt] = cvt8(p[0], p[1]);
        }
        bv[nt] = bi[wrow] + bh[wrow];
    }

    const int r0 = tid >> 2, q = tid & 3;
    const int swz = (r0 & 7) << 3;
    u64* dst = (u64*)xgT;

    for (int it = 0; it < 16; ++it) {
        int t = tc*16 + it;
        {
            int wd = words[r0*TB + t];
            const float4* p = (const float4*)(emb + (size_t)wd*EE + q*64);
            #pragma unroll
            for (int o = 0; o < 8; ++o) {
                float4 a = p[2*o], b2 = p[2*o + 1];
                *(bf16x8*)&x_s[r0][(q*64 + o*8) ^ swz] = cvt8(a, b2);
            }
        }
        __syncthreads();

        f32x4 acc[4][4];
        #pragma unroll
        for (int rt = 0; rt < 4; ++rt)
            #pragma unroll
            for (int nt = 0; nt < 4; ++nt)
                acc[rt][nt] = (f32x4){ bv[nt], bv[nt], bv[nt], bv[nt] };
        #pragma unroll
        for (int kt = 0; kt < 8; ++kt) {
            #pragma unroll
            for (int rt = 0; rt < 4; ++rt) {
                bf16x8 a = *(const bf16x8*)&x_s[rt*16 + cl][(kt*32 + kgrp*8) ^ ((cl & 7) << 3)];
                #pragma unroll
                for (int nt = 0; nt < 4; ++nt)
                    acc[rt][nt] = __builtin_amdgcn_mfma_f32_16x16x32_bf16(a, wf[kt][nt], acc[rt][nt], 0, 0, 0);
            }
        }
        #pragma unroll
        for (int nt = 0; nt < 4; ++nt) {
            int col = cc*256 + wv*64 + nt*16 + cl;
            #pragma unroll
            for (int rt = 0; rt < 4; ++rt) {
                f32x4 v = acc[rt][nt];
                u64 pkk =  (u64)(bfbits(v[0]))
                        | ((u64)(bfbits(v[1])) << 16)
                        | ((u64)(bfbits(v[2])) << 32)
                        | ((u64)(bfbits(v[3])) << 48);
                dst[(size_t)(t*GCOLS + col)*16 + rt*4 + kgrp] = pkk;
            }
        }
        __syncthreads();
    }
}

// ---------------- Phase 2: persistent recurrence, fragment-direct ----------------
__global__ __launch_bounds__(NT, 1)
void lstm_main(const float* __restrict__ Wh,
               const float* __restrict__ Wfc,
               const float* __restrict__ bfc,
               float* __restrict__ out,        // [64] head + [64*512] h (fp32)
               u64* __restrict__ fastH,        // [2][NB][NPAIR] tagged pairs (sc0)
               u64* __restrict__ slowH,        // [2][NB][NPAIR] tagged pairs (agent)
               const u64* __restrict__ xg64)   // xg[t][col][batchquad]
{
    const int tid  = threadIdx.x;
    const int lane = tid & 63;
    const int wv   = tid >> 6;        // 0..3
    const int g    = blockIdx.x >> 3; // domain (chunked: 8 consecutive blocks)
    const int ug   = blockIdx.x & 7;  // unit group 0..7 (64 units each)
    const int kgrp = lane >> 4;
    const int cl   = lane & 15;       // A row = batch g*16+cl (ALL 16 live)

    __shared__ __align__(16) float P_lds[16][NCOLP];

    // ---- Wh fragments: 4 n-tiles per wave (256 cols per block) ----
    bf16x8 whf[16][4];
    #pragma unroll
    for (int nt = 0; nt < 4; ++nt) {
        int gc = ug*256 + wv*64 + nt*16 + cl;
        int wrow = (gc & 3)*HH + (gc >> 2);
        const float* wr = Wh + (size_t)wrow*HH;
        #pragma unroll
        for (int kt = 0; kt < 16; ++kt) {
            const float4* p = (const float4*)(wr + kt*32 + kgrp*8);
            whf[kt][nt] = cvt8(p[0], p[1]);
        }
    }

    // xg addressing: all 4 D-rows live; quad m = g*4 + kgrp
    const int m = g*4 + kgrp;
    int gcv[4];
    #pragma unroll
    for (int nt = 0; nt < 4; ++nt) gcv[nt] = ug*256 + wv*64 + nt*16 + cl;

    u64 xgc[4], xgn[4];
    #pragma unroll
    for (int nt = 0; nt < 4; ++nt) xgc[nt] = xg64[(size_t)gcv[nt]*16 + m];

    // act roles: thread owns (batch b, 4 units ug*64 + us*4 ..)
    const int ab = tid >> 4, us = tid & 15;
    float cs0 = 0.f, cs1 = 0.f, cs2 = 0.f, cs3 = 0.f;

    __syncthreads();

    for (int t = 0; t < TB; ++t) {
        // ---- xg(t+1) prefetch (plain loads; drained by first frag wait) ----
        if (t + 1 < TB) {
            #pragma unroll
            for (int nt = 0; nt < 4; ++nt)
                xgn[nt] = xg64[(size_t)((t + 1)*GCOLS + gcv[nt])*16 + m];
        }

        f32x4 acc[4];
        #pragma unroll
        for (int nt = 0; nt < 4; ++nt) acc[nt] = cvtxg(xgc[nt]);

        // ---- fragment-direct recurrent MFMAs (groups of 4 kt, 1 ahead) ----
        if (t > 0) {
            size_t poff = ((size_t)((t & 1) ^ 1))*NB*NPAIR + (size_t)(g*DB + cl)*NPAIR;
            const u64* fb  = fastH + poff;
            const u64* sb2 = slowH + poff;
            u32x4 q[8];
            frag_issue((u64)fb*1 + (size_t)kgrp*32 + 0, q);   // group 0
            #pragma unroll
            for (int grp = 0; grp < 4; ++grp) {
                u64 fa = (u64)fb + (size_t)grp*512 + (size_t)kgrp*32;
                frag_get(fa, sb2 + grp*64 + kgrp*4, (u32)t, q);
                bf16x8 af[4];
                union U { u32 w[4]; bf16x8 v; };
                {
                    U u0; u0.w[0]=q[0][0]; u0.w[1]=q[0][2]; u0.w[2]=q[1][0]; u0.w[3]=q[1][2]; af[0]=u0.v;
                    U u1; u1.w[0]=q[2][0]; u1.w[1]=q[2][2]; u1.w[2]=q[3][0]; u1.w[3]=q[3][2]; af[1]=u1.v;
                    U u2; u2.w[0]=q[4][0]; u2.w[1]=q[4][2]; u2.w[2]=q[5][0]; u2.w[3]=q[5][2]; af[2]=u2.v;
                    U u3; u3.w[0]=q[6][0]; u3.w[1]=q[6][2]; u3.w[2]=q[7][0]; u3.w[3]=q[7][2]; af[3]=u3.v;
                }
                if (grp < 3)
                    frag_issue((u64)fb + (size_t)(grp + 1)*512 + (size_t)kgrp*32, q);
                #pragma unroll
                for (int j = 0; j < 4; ++j) {
                    int kt = grp*4 + j;
                    #pragma unroll
                    for (int nt = 0; nt < 4; ++nt)
                        acc[nt] = __builtin_amdgcn_mfma_f32_16x16x32_bf16(af[j], whf[kt][nt], acc[nt], 0, 0, 0);
                }
            }
        }

        // ---- preactivations: row = kgrp*4+r (batch), col = local gate-col ----
        #pragma unroll
        for (int nt = 0; nt < 4; ++nt)
            #pragma unroll
            for (int r = 0; r < 4; ++r)
                P_lds[kgrp*4 + r][wv*64 + nt*16 + cl] = acc[nt][r];
        bar_lds();   // B2 (lgkm only)

        // ---- activations: thread owns (batch ab, units ug*64 + us*4 ..+4) ----
        {
            float4 p0 = *(const float4*)&P_lds[ab][us*16 + 0];
            float4 p1 = *(const float4*)&P_lds[ab][us*16 + 4];
            float4 p2 = *(const float4*)&P_lds[ab][us*16 + 8];
            float4 p3 = *(const float4*)&P_lds[ab][us*16 + 12];
            float h0, h1, h2, h3;
            { float r=sigf(p0.x), f=sigf(p0.y), z=tanhfast(p0.z), o=sigf(p0.w);
              cs0 = f*cs0 + r*z; h0 = o*tanhfast(cs0); }
            { float r=sigf(p1.x), f=sigf(p1.y), z=tanhfast(p1.z), o=sigf(p1.w);
              cs1 = f*cs1 + r*z; h1 = o*tanhfast(cs1); }
            { float r=sigf(p2.x), f=sigf(p2.y), z=tanhfast(p2.z), o=sigf(p2.w);
              cs2 = f*cs2 + r*z; h2 = o*tanhfast(cs2); }
            { float r=sigf(p3.x), f=sigf(p3.y), z=tanhfast(p3.z), o=sigf(p3.w);
              cs3 = f*cs3 + r*z; h3 = o*tanhfast(cs3); }
            if (t == TB - 1) {
                float4 hw = { h0, h1, h2, h3 };
                *(float4*)&out[64 + (size_t)(g*DB + ab)*HH + ug*64 + us*4] = hw;
            }
            // dual publish: 2 tagged u64 pairs
            u64 tg = ((u64)(u32)(t + 1)) << 32;
            u64 v0 = tg | (u64)(bfbits(h0) | (bfbits(h1) << 16));
            u64 v1 = tg | (u64)(bfbits(h2) | (bfbits(h3) << 16));
            size_t di = ((size_t)(t & 1))*NB*NPAIR
                      + (size_t)(g*DB + ab)*NPAIR + ug*32 + us*2;
            asm volatile(
                "global_store_dwordx2 %0, %1, off sc0\n\t"
                "global_store_dwordx2 %0, %2, off offset:8 sc0"
                :: "v"((u64)(fastH + di)), "v"(v0), "v"(v1) : "memory");
            __hip_atomic_store(slowH + di,     v0, __ATOMIC_RELAXED, __HIP_MEMORY_SCOPE_AGENT);
            __hip_atomic_store(slowH + di + 1, v1, __ATOMIC_RELAXED, __HIP_MEMORY_SCOPE_AGENT);
        }
        bar_lds();   // B3: P_lds WAR (lgkm only; publish stores stay in flight)
        #pragma unroll
        for (int nt = 0; nt < 4; ++nt) xgc[nt] = xgn[nt];
    }

    // ---- final FC head: block ug==0 of each domain ----
    if (ug == 0) {
        __syncthreads();
        int b = tid >> 4, seg = tid & 15;
        const u64* sp = slowH + (size_t)1*NB*NPAIR + (size_t)(g*DB + b)*NPAIR + seg*16;
        u64 hv[16];
        for (;;) {
            bool ok = true;
            #pragma unroll
            for (int j = 0; j < 16; ++j) {
                hv[j] = __hip_atomic_load(sp + j, __ATOMIC_RELAXED, __HIP_MEMORY_SCOPE_AGENT);
                ok &= ((u32)(hv[j] >> 32) == (u32)TB);
            }
            if (ok) break;
            __builtin_amdgcn_s_sleep(1);
        }
        float s = 0.f;
        #pragma unroll
        for (int j = 0; j < 16; ++j) {
            u32 pl = (u32)hv[j];
            int u = seg*32 + 2*j;
            s += __uint_as_float((pl & 0xFFFFu) << 16) * Wfc[u];
            s += __uint_as_float(pl & 0xFFFF0000u)     * Wfc[u + 1];
        }
        P_lds[b][seg] = s;
        __syncthreads();
        if (tid < 16) {
            float acc = 0.f;
            #pragma unroll
            for (int q2 = 0; q2 < 16; ++q2) acc += P_lds[tid][q2];
            out[g*DB + tid] = sigf(acc + bfc[0]);
        }
    }
}

extern "C" void kernel_launch(void* const* d_in, const int* in_sizes, int n_in,
                              void* d_out, int out_size, void* d_ws, size_t ws_size,
                              hipStream_t stream) {
    (void)in_sizes; (void)n_in; (void)out_size; (void)ws_size;
    const int*   words = (const int*)d_in[0];
    const float* emb   = (const float*)d_in[1];
    const float* Wi    = (const float*)d_in[2];
    const float* bi    = (const float*)d_in[3];
    const float* Wh    = (const float*)d_in[4];
    const float* bh    = (const float*)d_in[5];
    const float* Wfc   = (const float*)d_in[6];
    const float* bfc   = (const float*)d_in[7];
    float* out = (float*)d_out;

    u64* fastH  = (u64*)d_ws;
    u64* slowH  = (u64*)((char*)d_ws + SLOWOFF);
    bf16_t* xgT = (bf16_t*)((char*)d_ws + XGOFF);

    // zero both tag buffers every launch (tag 0 matches no step)
    hipMemsetAsync(d_ws, 0, 2*SLOWOFF, stream);

    xg_prepass<<<dim3(256), dim3(256), 0, stream>>>(words, emb, Wi, bi, bh, xgT);
    lstm_main<<<dim3(ND*NBLK), dim3(NT), 0, stream>>>(Wh, Wfc, bfc, out,
                                                      fastH, slowH, (const u64*)xgT);
}

// Round 15
// 3381.416 us; speedup vs baseline: 1.9213x; 1.9213x over previous
//
#include <hip/hip_runtime.h>
#include <hip/hip_bf16.h>

// LSTM: B=64, T=512, V=32000, E=256, H=512, O=1
// R15: producer-consumer wave specialization (clean re-test of the
// store-drain theory; R13's test was confounded by a whf spill).
//   block = 512 thr / 8 waves: waves 0-3 compute (R9's exact path),
//   waves 4-7 poll tagged h into a DOUBLE-BUFFERED h_lds (never store).
//   Compute waves never vmcnt-wait on the critical path: publish stores
//   fire-and-forget (ack during B_end), xg drains after a barrier of slack.
// Geometry: 8 domains x 8 batches x 8 blocks, chunked mapping (R11).
// Exchange: R9's dual-protocol tagged u64 (sc0 hot + agent probe), verbatim.
#define TB 512
#define NB 64
#define EE 256
#define HH 512
#define ND 8           // sync domains
#define DB 8           // batches per domain
#define NBLK 8         // blocks per domain
#define NT 512         // 4 compute waves + 4 IO waves
#define NCOLP 260      // P_lds padded row (floats)
#define NPAIR 256      // h pairs per batch
#define GCOLS 2048
#define SLOWOFF ((size_t)0x40000)  // slow buffer offset (fast at 0, 256KB each)
#define XGOFF   ((size_t)1 << 20)  // xg offset in d_ws

typedef __bf16 bf16_t;
typedef bf16_t bf16x8 __attribute__((ext_vector_type(8)));
typedef float  f32x4  __attribute__((ext_vector_type(4)));
typedef unsigned u32;
typedef unsigned long long u64;
typedef u32 u32x4 __attribute__((ext_vector_type(4)));

__device__ __forceinline__ float sigf(float x) { return 1.0f / (1.0f + __expf(-x)); }
__device__ __forceinline__ float tanhfast(float x) {
    float xc = fminf(fmaxf(x, -15.0f), 15.0f);
    float e  = __expf(2.0f * xc);
    return (e - 1.0f) / (e + 1.0f);
}
__device__ __forceinline__ u32 bfbits(float f) {
    bf16_t h = (bf16_t)f;
    return (u32)__builtin_bit_cast(unsigned short, h);
}
__device__ __forceinline__ bf16x8 cvt8(float4 a, float4 b) {
    bf16x8 v;
    v[0]=(bf16_t)a.x; v[1]=(bf16_t)a.y; v[2]=(bf16_t)a.z; v[3]=(bf16_t)a.w;
    v[4]=(bf16_t)b.x; v[5]=(bf16_t)b.y; v[6]=(bf16_t)b.z; v[7]=(bf16_t)b.w;
    return v;
}
__device__ __forceinline__ f32x4 cvtxg(u64 v) {
    f32x4 r;
    r[0] = __uint_as_float((u32)( v        & 0xFFFFu) << 16);
    r[1] = __uint_as_float((u32)((v >> 16) & 0xFFFFu) << 16);
    r[2] = __uint_as_float((u32)((v >> 32) & 0xFFFFu) << 16);
    r[3] = __uint_as_float((u32)((v >> 48) & 0xFFFFu) << 16);
    return r;
}

// LDS-only barrier (lgkm drain + s_barrier): vmem stays in flight.
__device__ __forceinline__ void bar_lds() {
    __builtin_amdgcn_sched_barrier(0);
    asm volatile("s_waitcnt lgkmcnt(0)" ::: "memory");
    __builtin_amdgcn_s_barrier();
    __builtin_amdgcn_sched_barrier(0);
}

// Dual poll of 8 tagged u64s (64B): hot-spin sc0 (L2), agent probe every 4th.
__device__ __forceinline__ void poll8_dual(const u64* fsrc, const u64* ssrc,
                                           u32 tag, u64 (&pk)[4]) {
    u64 fa = (u64)fsrc;
    int it = 0;
    for (;;) {
        u32x4 q0, q1, q2, q3;
        asm volatile(
            "global_load_dwordx4 %0, %4, off sc0\n\t"
            "global_load_dwordx4 %1, %4, off offset:16 sc0\n\t"
            "global_load_dwordx4 %2, %4, off offset:32 sc0\n\t"
            "global_load_dwordx4 %3, %4, off offset:48 sc0\n\t"
            "s_waitcnt vmcnt(0)"
            : "=&v"(q0), "=&v"(q1), "=&v"(q2), "=&v"(q3)
            : "v"(fa)
            : "memory");
        if (q0[1]==tag && q0[3]==tag && q1[1]==tag && q1[3]==tag &&
            q2[1]==tag && q2[3]==tag && q3[1]==tag && q3[3]==tag) {
            pk[0] = (u64)q0[0] | ((u64)q0[2] << 32);
            pk[1] = (u64)q1[0] | ((u64)q1[2] << 32);
            pk[2] = (u64)q2[0] | ((u64)q2[2] << 32);
            pk[3] = (u64)q3[0] | ((u64)q3[2] << 32);
            return;
        }
        if (((++it) & 3) == 0) {
            u64 hv[8];
            #pragma unroll
            for (int j = 0; j < 8; ++j)
                hv[j] = __hip_atomic_load(ssrc + j, __ATOMIC_RELAXED, __HIP_MEMORY_SCOPE_AGENT);
            bool ok = true;
            #pragma unroll
            for (int j = 0; j < 8; ++j) ok &= ((u32)(hv[j] >> 32) == tag);
            if (ok) {
                #pragma unroll
                for (int k = 0; k < 4; ++k)
                    pk[k] = (u64)(u32)hv[2*k] | ((u64)(u32)hv[2*k + 1] << 32);
                return;
            }
        }
    }
}

// ---------------- Phase 1: xg pre-pass GEMM (proven R7, verbatim) ----------------
__global__ __launch_bounds__(256, 1)
void xg_prepass(const int* __restrict__ words, const float* __restrict__ emb,
                const float* __restrict__ Wi, const float* __restrict__ bi,
                const float* __restrict__ bh, bf16_t* __restrict__ xgT)
{
    const int tid = threadIdx.x, lane = tid & 63, wv = tid >> 6;
    const int kgrp = lane >> 4, cl = lane & 15;
    const int cc = blockIdx.x & 7, tc = blockIdx.x >> 3;

    __shared__ __align__(16) bf16_t x_s[64][EE];

    bf16x8 wf[8][4];
    float  bv[4];
    #pragma unroll
    for (int nt = 0; nt < 4; ++nt) {
        int col = cc*256 + wv*64 + nt*16 + cl;
        int wrow = (col & 3)*HH + (col >> 2);
        const float* wr = Wi + (size_t)wrow*EE;
        #pragma unroll
        for (int kt = 0; kt < 8; ++kt) {
            const float4* p = (const float4*)(wr + kt*32 + kgrp*8);
            wf[kt][nt] = cvt8(p[0], p[1]);
        }
        bv[nt] = bi[wrow] + bh[wrow];
    }

    const int r0 = tid >> 2, q = tid & 3;
    const int swz = (r0 & 7) << 3;
    u64* dst = (u64*)xgT;

    for (int it = 0; it < 16; ++it) {
        int t = tc*16 + it;
        {
            int wd = words[r0*TB + t];
            const float4* p = (const float4*)(emb + (size_t)wd*EE + q*64);
            #pragma unroll
            for (int o = 0; o < 8; ++o) {
                float4 a = p[2*o], b2 = p[2*o + 1];
                *(bf16x8*)&x_s[r0][(q*64 + o*8) ^ swz] = cvt8(a, b2);
            }
        }
        __syncthreads();

        f32x4 acc[4][4];
        #pragma unroll
        for (int rt = 0; rt < 4; ++rt)
            #pragma unroll
            for (int nt = 0; nt < 4; ++nt)
                acc[rt][nt] = (f32x4){ bv[nt], bv[nt], bv[nt], bv[nt] };
        #pragma unroll
        for (int kt = 0; kt < 8; ++kt) {
            #pragma unroll
            for (int rt = 0; rt < 4; ++rt) {
                bf16x8 a = *(const bf16x8*)&x_s[rt*16 + cl][(kt*32 + kgrp*8) ^ ((cl & 7) << 3)];
                #pragma unroll
                for (int nt = 0; nt < 4; ++nt)
                    acc[rt][nt] = __builtin_amdgcn_mfma_f32_16x16x32_bf16(a, wf[kt][nt], acc[rt][nt], 0, 0, 0);
            }
        }
        #pragma unroll
        for (int nt = 0; nt < 4; ++nt) {
            int col = cc*256 + wv*64 + nt*16 + cl;
            #pragma unroll
            for (int rt = 0; rt < 4; ++rt) {
                f32x4 v = acc[rt][nt];
                u64 pkk =  (u64)(bfbits(v[0]))
                        | ((u64)(bfbits(v[1])) << 16)
                        | ((u64)(bfbits(v[2])) << 32)
                        | ((u64)(bfbits(v[3])) << 48);
                dst[(size_t)(t*GCOLS + col)*16 + rt*4 + kgrp] = pkk;
            }
        }
        __syncthreads();
    }
}

// ---------------- Phase 2: persistent recurrence, wave-specialized ----------------
__global__ __launch_bounds__(NT, 1)
void lstm_main(const float* __restrict__ Wh,
               const float* __restrict__ Wfc,
               const float* __restrict__ bfc,
               float* __restrict__ out,        // [64] head + [64*512] h (fp32)
               u64* __restrict__ fastH,        // [2][NB][NPAIR] tagged pairs (sc0)
               u64* __restrict__ slowH,        // [2][NB][NPAIR] tagged pairs (agent)
               const u64* __restrict__ xg64)   // xg[t][col][batchquad]
{
    const int tid  = threadIdx.x;
    const int lane = tid & 63;
    const int wv   = tid >> 6;        // 0..7
    const int wvm  = wv & 3;          // uniform addressing for whf (all waves load)
    const int g    = blockIdx.x >> 3; // domain (chunked: 8 consecutive blocks)
    const int ug   = blockIdx.x & 7;  // unit group 0..7 (64 units each)
    const int kgrp = lane >> 4;
    const int cl   = lane & 15;
    const bool cw  = (wv < 4);        // compute wave?

    __shared__ __align__(16) bf16_t h_lds[2][16][HH];  // double-buffered, rows 8..15 zero
    __shared__ __align__(16) float  P_lds[16][NCOLP];

    // zero both h buffers (h_{-1}=0; rows 8..15 stay zero forever)
    for (int i = tid; i < 2*16*HH/2; i += NT) ((u32*)h_lds)[i] = 0u;

    // ---- Wh fragments: loaded UNCONDITIONALLY (uniform codegen; wvm keeps
    //      IO waves' addresses in-bounds as duplicates of compute waves) ----
    bf16x8 whf[16][4];
    #pragma unroll
    for (int nt = 0; nt < 4; ++nt) {
        int gc = ug*256 + wvm*64 + nt*16 + cl;
        int wrow = (gc & 3)*HH + (gc >> 2);
        const float* wr = Wh + (size_t)wrow*HH;
        #pragma unroll
        for (int kt = 0; kt < 16; ++kt) {
            const float4* p = (const float4*)(wr + kt*32 + kgrp*8);
            whf[kt][nt] = cvt8(p[0], p[1]);
        }
    }

    // compute roles: act thread (batch sb, units 2*sc,2*sc+1)
    const int sb = (tid >> 5) & 7, sc = tid & 31;
    // IO roles: thread 256+i polls (batch iob, chunk ioc)
    const int io  = tid - 256;
    const int iob = (io >> 5) & 7, ioc = io & 31;
    const int ioswz = (iob & 7) << 3;

    // xg addressing (compute waves only)
    const int m = 2*g + (kgrp & 1);
    int gcv[4];
    #pragma unroll
    for (int nt = 0; nt < 4; ++nt) gcv[nt] = ug*256 + wvm*64 + nt*16 + cl;

    u64 xgc[4] = {0,0,0,0}, xgn[4] = {0,0,0,0};
    if (cw) {
        #pragma unroll
        for (int nt = 0; nt < 4; ++nt) xgc[nt] = xg64[(size_t)gcv[nt]*16 + m];
    }

    float c0 = 0.f, c1 = 0.f;
    __syncthreads();

    for (int t = 0; t < TB; ++t) {
        // ---- compute: MFMA from h_lds[(t&1)^1] (holds h_{t-1}) ----
        if (cw) {
            f32x4 acc[4];
            #pragma unroll
            for (int nt = 0; nt < 4; ++nt) acc[nt] = cvtxg(xgc[nt]);
            if (t > 0) {
                const bf16_t (*hb)[HH] = h_lds[(t & 1) ^ 1];
                #pragma unroll
                for (int kt = 0; kt < 16; ++kt) {
                    bf16x8 a = *(const bf16x8*)&hb[cl][(kt*32 + kgrp*8) ^ ((cl & 7) << 3)];
                    #pragma unroll
                    for (int nt = 0; nt < 4; ++nt)
                        acc[nt] = __builtin_amdgcn_mfma_f32_16x16x32_bf16(a, whf[kt][nt], acc[nt], 0, 0, 0);
                }
            }
            #pragma unroll
            for (int nt = 0; nt < 4; ++nt)
                #pragma unroll
                for (int r = 0; r < 4; ++r)
                    P_lds[kgrp*4 + r][wvm*64 + nt*16 + cl] = acc[nt][r];
        }
        bar_lds();   // B2: P visible (IO arrives immediately)

        if (cw) {
            // ---- act + publish (fire-and-forget: no vmcnt drain follows) ----
            float4 g0 = *(const float4*)&P_lds[sb][sc*8];
            float4 g1 = *(const float4*)&P_lds[sb][sc*8 + 4];
            float r0 = sigf(g0.x), f0 = sigf(g0.y), z0 = tanhfast(g0.z), o0 = sigf(g0.w);
            float r1 = sigf(g1.x), f1 = sigf(g1.y), z1 = tanhfast(g1.z), o1 = sigf(g1.w);
            c0 = f0*c0 + r0*z0;
            c1 = f1*c1 + r1*z1;
            float h0 = o0*tanhfast(c0);
            float h1 = o1*tanhfast(c1);
            if (t == TB - 1) {
                float2 hw = { h0, h1 };
                *(float2*)&out[64 + (size_t)(g*DB + sb)*HH + ug*64 + 2*sc] = hw;
            }
            u64 v = (((u64)(u32)(t + 1)) << 32)
                  | (u64)(bfbits(h0) | (bfbits(h1) << 16));
            size_t di = ((size_t)(t & 1))*NB*NPAIR
                      + (size_t)(g*DB + sb)*NPAIR + ug*32 + sc;
            asm volatile("global_store_dwordx2 %0, %1, off sc0"
                         :: "v"((u64)(fastH + di)), "v"(v) : "memory");
            __hip_atomic_store(slowH + di, v, __ATOMIC_RELAXED, __HIP_MEMORY_SCOPE_AGENT);
            // xg(t+1) prefetch: issued after stores; drains at next seed,
            // after B_end has given it (and the stores) a full wait of slack
            if (t + 1 < TB) {
                #pragma unroll
                for (int nt = 0; nt < 4; ++nt)
                    xgn[nt] = xg64[(size_t)((t + 1)*GCOLS + gcv[nt])*16 + m];
            }
            #pragma unroll
            for (int nt = 0; nt < 4; ++nt) xgc[nt] = xgn[nt];
        } else if (t + 1 < TB) {
            // ---- IO: poll h_t (tag t+1) into h_lds[t&1]; overlaps producers'
            //      act+publish+transit; own vmem queue has only poll loads ----
            size_t off = ((size_t)(t & 1))*NB*NPAIR
                       + (size_t)(g*DB + iob)*NPAIR + ioc*8;
            u64 pk[4];
            poll8_dual(fastH + off, slowH + off, (u32)(t + 1), pk);
            #pragma unroll
            for (int k = 0; k < 4; ++k) {
                int e = ioc*16 + 4*k;
                int phys = ((e & ~7) ^ ioswz) | (e & 7);
                *(u64*)&h_lds[t & 1][iob][phys] = pk[k];
            }
        }
        bar_lds();   // B_end: h_lds[t&1] complete -> next iter may read it
    }

    // ---- final FC head: block ug==0 of each domain (slow-buffer read) ----
    if (ug == 0) {
        float s = 0.f;
        if (tid < 256) {
            const u64* sp = slowH + ((size_t)((TB - 1) & 1))*NB*NPAIR
                          + (size_t)(g*DB + sb)*NPAIR + sc*8;
            u64 hv[8];
            for (;;) {
                bool ok = true;
                #pragma unroll
                for (int j = 0; j < 8; ++j) {
                    hv[j] = __hip_atomic_load(sp + j, __ATOMIC_RELAXED, __HIP_MEMORY_SCOPE_AGENT);
                    ok &= ((u32)(hv[j] >> 32) == (u32)TB);
                }
                if (ok) break;
                __builtin_amdgcn_s_sleep(1);
            }
            const float4* wp = (const float4*)(Wfc + sc*16);
            #pragma unroll
            for (int k = 0; k < 4; ++k) {
                float4 w = wp[k];
                u64 p = hv[2*k] | 0ull;
                u64 p2 = hv[2*k + 1];
                s += __uint_as_float((u32)( p        & 0xFFFFu) << 16) * w.x;
                s += __uint_as_float((u32)((p >> 16) & 0xFFFFu) << 16) * w.y;
                s += __uint_as_float((u32)( p2        & 0xFFFFu) << 16) * w.z;
                s += __uint_as_float((u32)((p2 >> 16) & 0xFFFFu) << 16) * w.w;
            }
        }
        __syncthreads();
        if (tid < 256) P_lds[sb][sc] = s;
        __syncthreads();
        if (tid < 8) {
            float acc = 0.f;
            #pragma unroll
            for (int q2 = 0; q2 < 32; ++q2) acc += P_lds[tid][q2];
            out[g*DB + tid] = sigf(acc + bfc[0]);
        }
    }
}

extern "C" void kernel_launch(void* const* d_in, const int* in_sizes, int n_in,
                              void* d_out, int out_size, void* d_ws, size_t ws_size,
                              hipStream_t stream) {
    (void)in_sizes; (void)n_in; (void)out_size; (void)ws_size;
    const int*   words = (const int*)d_in[0];
    const float* emb   = (const float*)d_in[1];
    const float* Wi    = (const float*)d_in[2];
    const float* bi    = (const float*)d_in[3];
    const float* Wh    = (const float*)d_in[4];
    const float* bh    = (const float*)d_in[5];
    const float* Wfc   = (const float*)d_in[6];
    const float* bfc   = (const float*)d_in[7];
    float* out = (float*)d_out;

    u64* fastH  = (u64*)d_ws;
    u64* slowH  = (u64*)((char*)d_ws + SLOWOFF);
    bf16_t* xgT = (bf16_t*)((char*)d_ws + XGOFF);

    // zero both tag buffers every launch (tag 0 matches no step)
    hipMemsetAsync(d_ws, 0, 2*SLOWOFF, stream);

    xg_prepass<<<dim3(256), dim3(256), 0, stream>>>(words, emb, Wi, bi, bh, xgT);
    lstm_main<<<dim3(ND*NBLK), dim3(NT), 0, stream>>>(Wh, Wfc, bfc, out,
                                                      fastH, slowH, (const u64*)xgT);
}

// Round 16
// 2151.915 us; speedup vs baseline: 3.0190x; 1.5714x over previous
//
#include <hip/hip_runtime.h>
#include <hip/hip_bf16.h>

// LSTM: B=64, T=512, V=32000, E=256, H=512, O=1
// R16 = R9 (best: 2017us) + two micro-levers, everything else verbatim:
//   (1) poll hot-spins sc0 with NO s_sleep (agent probe every 4th round);
//   (2) act phase computes h then publishes IMMEDIATELY (agent store first),
//       deferring out[] epilogue + xg prefetch until stores are in flight.
// Dual-protocol tagged exchange: u64 = tag<<32 | 2xbf16, stored sc0 (fast,
// L2-visible if co-XCD) + agent-scope (MALL, always visible). Tags ride with
// data -> self-validating; liveness never depends on XCD placement.
// 8 domains (8 batches) x 8 blocks (domain = blockIdx&7) x 256 thr.
#define TB 512
#define NB 64
#define EE 256
#define HH 512
#define ND 8           // sync domains
#define DB 8           // batches per domain
#define NBLK 8         // blocks per domain
#define NT 256         // threads per block (4 waves)
#define NCOLP 260      // P_lds padded row (floats)
#define NPAIR 256      // h pairs per batch
#define GCOLS 2048
#define SLOWOFF ((size_t)0x40000)  // slow buffer offset (fast at 0, 256KB each)
#define XGOFF   ((size_t)1 << 20)  // xg offset in d_ws

typedef __bf16 bf16_t;
typedef bf16_t bf16x8 __attribute__((ext_vector_type(8)));
typedef float  f32x4  __attribute__((ext_vector_type(4)));
typedef unsigned u32;
typedef unsigned long long u64;
typedef u32 u32x4 __attribute__((ext_vector_type(4)));

__device__ __forceinline__ float sigf(float x) { return 1.0f / (1.0f + __expf(-x)); }
__device__ __forceinline__ float tanhfast(float x) {
    float xc = fminf(fmaxf(x, -15.0f), 15.0f);
    float e  = __expf(2.0f * xc);
    return (e - 1.0f) / (e + 1.0f);
}
__device__ __forceinline__ u32 bfbits(float f) {
    bf16_t h = (bf16_t)f;
    return (u32)__builtin_bit_cast(unsigned short, h);
}
__device__ __forceinline__ bf16x8 cvt8(float4 a, float4 b) {
    bf16x8 v;
    v[0]=(bf16_t)a.x; v[1]=(bf16_t)a.y; v[2]=(bf16_t)a.z; v[3]=(bf16_t)a.w;
    v[4]=(bf16_t)b.x; v[5]=(bf16_t)b.y; v[6]=(bf16_t)b.z; v[7]=(bf16_t)b.w;
    return v;
}
__device__ __forceinline__ f32x4 cvtxg(u64 v) {
    f32x4 r;
    r[0] = __uint_as_float((u32)( v        & 0xFFFFu) << 16);
    r[1] = __uint_as_float((u32)((v >> 16) & 0xFFFFu) << 16);
    r[2] = __uint_as_float((u32)((v >> 32) & 0xFFFFu) << 16);
    r[3] = __uint_as_float((u32)((v >> 48) & 0xFFFFu) << 16);
    return r;
}

// Dual poll of 8 tagged u64s (64B): hot-spin sc0 (NO sleep), agent probe
// every 4th round. Tags self-validate; agent rounds guarantee liveness.
__device__ __forceinline__ void poll8_dual(const u64* fsrc, const u64* ssrc,
                                           u32 tag, u64 (&pk)[4]) {
    u64 fa = (u64)fsrc;
    int it = 0;
    for (;;) {
        u32x4 q0, q1, q2, q3;
        asm volatile(
            "global_load_dwordx4 %0, %4, off sc0\n\t"
            "global_load_dwordx4 %1, %4, off offset:16 sc0\n\t"
            "global_load_dwordx4 %2, %4, off offset:32 sc0\n\t"
            "global_load_dwordx4 %3, %4, off offset:48 sc0\n\t"
            "s_waitcnt vmcnt(0)"
            : "=&v"(q0), "=&v"(q1), "=&v"(q2), "=&v"(q3)
            : "v"(fa)
            : "memory");
        if (q0[1]==tag && q0[3]==tag && q1[1]==tag && q1[3]==tag &&
            q2[1]==tag && q2[3]==tag && q3[1]==tag && q3[3]==tag) {
            pk[0] = (u64)q0[0] | ((u64)q0[2] << 32);
            pk[1] = (u64)q1[0] | ((u64)q1[2] << 32);
            pk[2] = (u64)q2[0] | ((u64)q2[2] << 32);
            pk[3] = (u64)q3[0] | ((u64)q3[2] << 32);
            return;
        }
        if (((++it) & 3) == 0) {
            u64 hv[8];
            #pragma unroll
            for (int j = 0; j < 8; ++j)
                hv[j] = __hip_atomic_load(ssrc + j, __ATOMIC_RELAXED, __HIP_MEMORY_SCOPE_AGENT);
            bool ok = true;
            #pragma unroll
            for (int j = 0; j < 8; ++j) ok &= ((u32)(hv[j] >> 32) == tag);
            if (ok) {
                #pragma unroll
                for (int k = 0; k < 4; ++k)
                    pk[k] = (u64)(u32)hv[2*k] | ((u64)(u32)hv[2*k + 1] << 32);
                return;
            }
        }
    }
}

// ---------------- Phase 1: xg pre-pass GEMM (proven R7, verbatim) ----------------
__global__ __launch_bounds__(256, 1)
void xg_prepass(const int* __restrict__ words, const float* __restrict__ emb,
                const float* __restrict__ Wi, const float* __restrict__ bi,
                const float* __restrict__ bh, bf16_t* __restrict__ xgT)
{
    const int tid = threadIdx.x, lane = tid & 63, wv = tid >> 6;
    const int kgrp = lane >> 4, cl = lane & 15;
    const int cc = blockIdx.x & 7, tc = blockIdx.x >> 3;

    __shared__ __align__(16) bf16_t x_s[64][EE];

    bf16x8 wf[8][4];
    float  bv[4];
    #pragma unroll
    for (int nt = 0; nt < 4; ++nt) {
        int col = cc*256 + wv*64 + nt*16 + cl;
        int wrow = (col & 3)*HH + (col >> 2);
        const float* wr = Wi + (size_t)wrow*EE;
        #pragma unroll
        for (int kt = 0; kt < 8; ++kt) {
            const float4* p = (const float4*)(wr + kt*32 + kgrp*8);
            wf[kt][nt] = cvt8(p[0], p[1]);
        }
        bv[nt] = bi[wrow] + bh[wrow];
    }

    const int r0 = tid >> 2, q = tid & 3;
    const int swz = (r0 & 7) << 3;
    u64* dst = (u64*)xgT;

    for (int it = 0; it < 16; ++it) {
        int t = tc*16 + it;
        {
            int wd = words[r0*TB + t];
            const float4* p = (const float4*)(emb + (size_t)wd*EE + q*64);
            #pragma unroll
            for (int o = 0; o < 8; ++o) {
                float4 a = p[2*o], b2 = p[2*o + 1];
                *(bf16x8*)&x_s[r0][(q*64 + o*8) ^ swz] = cvt8(a, b2);
            }
        }
        __syncthreads();

        f32x4 acc[4][4];
        #pragma unroll
        for (int rt = 0; rt < 4; ++rt)
            #pragma unroll
            for (int nt = 0; nt < 4; ++nt)
                acc[rt][nt] = (f32x4){ bv[nt], bv[nt], bv[nt], bv[nt] };
        #pragma unroll
        for (int kt = 0; kt < 8; ++kt) {
            #pragma unroll
            for (int rt = 0; rt < 4; ++rt) {
                bf16x8 a = *(const bf16x8*)&x_s[rt*16 + cl][(kt*32 + kgrp*8) ^ ((cl & 7) << 3)];
                #pragma unroll
                for (int nt = 0; nt < 4; ++nt)
                    acc[rt][nt] = __builtin_amdgcn_mfma_f32_16x16x32_bf16(a, wf[kt][nt], acc[rt][nt], 0, 0, 0);
            }
        }
        #pragma unroll
        for (int nt = 0; nt < 4; ++nt) {
            int col = cc*256 + wv*64 + nt*16 + cl;
            #pragma unroll
            for (int rt = 0; rt < 4; ++rt) {
                f32x4 v = acc[rt][nt];
                u64 pkk =  (u64)(bfbits(v[0]))
                        | ((u64)(bfbits(v[1])) << 16)
                        | ((u64)(bfbits(v[2])) << 32)
                        | ((u64)(bfbits(v[3])) << 48);
                dst[(size_t)(t*GCOLS + col)*16 + rt*4 + kgrp] = pkk;
            }
        }
        __syncthreads();
    }
}

// ---------------- Phase 2: persistent recurrence, dual-protocol exchange ----------------
__global__ __launch_bounds__(NT, 1)
void lstm_main(const float* __restrict__ Wh,
               const float* __restrict__ Wfc,
               const float* __restrict__ bfc,
               float* __restrict__ out,        // [64] head + [64*512] h (fp32)
               u64* __restrict__ fastH,        // [2][NB][NPAIR] tagged pairs (sc0)
               u64* __restrict__ slowH,        // [2][NB][NPAIR] tagged pairs (agent)
               const u64* __restrict__ xg64)   // xg[t][col][batchquad]
{
    const int tid  = threadIdx.x;
    const int lane = tid & 63;
    const int wv   = tid >> 6;        // 0..3
    const int g    = blockIdx.x & 7;  // domain (R9 mapping)
    const int ug   = blockIdx.x >> 3; // unit group 0..7 (64 units each)
    const int kgrp = lane >> 4;
    const int cl   = lane & 15;

    __shared__ __align__(16) bf16_t h_lds[16][HH];    // rows 8..15 stay zero
    __shared__ __align__(16) float  P_lds[16][NCOLP];

    // zero h_lds (h_{-1}=0)
    for (int i = tid; i < 16*HH/2; i += NT) ((u32*)h_lds)[i] = 0u;

    // ---- Wh fragments: 4 n-tiles per wave (256 local cols per block) ----
    bf16x8 whf[16][4];
    #pragma unroll
    for (int nt = 0; nt < 4; ++nt) {
        int gc = ug*256 + wv*64 + nt*16 + cl;       // global gate-col
        int wrow = (gc & 3)*HH + (gc >> 2);
        const float* wr = Wh + (size_t)wrow*HH;
        #pragma unroll
        for (int kt = 0; kt < 16; ++kt) {
            const float4* p = (const float4*)(wr + kt*32 + kgrp*8);
            whf[kt][nt] = cvt8(p[0], p[1]);
        }
    }

    // thread roles for poll/act: batch sb (0..7), chunk sc (0..31)
    const int sb = tid >> 5, sc = tid & 31;
    const int swz = sb << 3;

    // xg addressing: quad m covers batches 4m..4m+3; local rows kgrp*4+r
    const int m = 2*g + (kgrp & 1);
    int gc[4];
    #pragma unroll
    for (int nt = 0; nt < 4; ++nt) gc[nt] = ug*256 + wv*64 + nt*16 + cl;

    u64 xgc[4], xgn[4];
    #pragma unroll
    for (int nt = 0; nt < 4; ++nt) xgc[nt] = xg64[(size_t)gc[nt]*16 + m];

    float c0 = 0.f, c1 = 0.f;
    __syncthreads();

    for (int t = 0; t < TB; ++t) {
        // ---- poll tagged h_{t-1} (8 pairs from one producer), stage to LDS ----
        if (t > 0) {
            size_t off = ((size_t)((t & 1) ^ 1))*NB*NPAIR
                       + (size_t)(g*DB + sb)*NPAIR + sc*8;
            u64 pk[4];
            poll8_dual(fastH + off, slowH + off, (u32)t, pk);
            #pragma unroll
            for (int k = 0; k < 4; ++k) {
                int e = sc*16 + 4*k;
                int phys = ((e & ~7) ^ swz) | (e & 7);
                *(u64*)&h_lds[sb][phys] = pk[k];
            }
        }

        // ---- prefetch xg(t+1): sequential, one full step of slack ----
        if (t + 1 < TB) {
            #pragma unroll
            for (int nt = 0; nt < 4; ++nt)
                xgn[nt] = xg64[(size_t)((t + 1)*GCOLS + gc[nt])*16 + m];
        }
        __syncthreads();   // B1: h_lds visible

        // ---- recurrent MFMAs, acc seeded from xg (bias pre-folded) ----
        f32x4 acc[4];
        #pragma unroll
        for (int nt = 0; nt < 4; ++nt) acc[nt] = cvtxg(xgc[nt]);
        if (t > 0) {
            #pragma unroll
            for (int kt = 0; kt < 16; ++kt) {
                bf16x8 a = *(const bf16x8*)&h_lds[cl][(kt*32 + kgrp*8) ^ ((cl & 7) << 3)];
                #pragma unroll
                for (int nt = 0; nt < 4; ++nt)
                    acc[nt] = __builtin_amdgcn_mfma_f32_16x16x32_bf16(a, whf[kt][nt], acc[nt], 0, 0, 0);
            }
        }

        // ---- preactivations: row = kgrp*4+r (local batch), col = local gate-col ----
        #pragma unroll
        for (int nt = 0; nt < 4; ++nt)
            #pragma unroll
            for (int r = 0; r < 4; ++r)
                P_lds[kgrp*4 + r][wv*64 + nt*16 + cl] = acc[nt][r];
        __syncthreads();   // B2: P visible

        // ---- activations: compute h FIRST, publish IMMEDIATELY (agent store
        //      first: it is the long pole), then epilogue + next-xg prefetch ----
        {
            float4 g0 = *(const float4*)&P_lds[sb][sc*8];
            float4 g1 = *(const float4*)&P_lds[sb][sc*8 + 4];
            float r0 = sigf(g0.x), f0 = sigf(g0.y), z0 = tanhfast(g0.z), o0 = sigf(g0.w);
            float r1 = sigf(g1.x), f1 = sigf(g1.y), z1 = tanhfast(g1.z), o1 = sigf(g1.w);
            c0 = f0*c0 + r0*z0;
            c1 = f1*c1 + r1*z1;
            float h0 = o0*tanhfast(c0);
            float h1 = o1*tanhfast(c1);

            u64 v = (((u64)(u32)(t + 1)) << 32)
                  | (u64)(bfbits(h0) | (bfbits(h1) << 16));
            size_t di = ((size_t)(t & 1))*NB*NPAIR
                      + (size_t)(g*DB + sb)*NPAIR + ug*32 + sc;
            __hip_atomic_store(slowH + di, v, __ATOMIC_RELAXED, __HIP_MEMORY_SCOPE_AGENT);
            asm volatile("global_store_dwordx2 %0, %1, off sc0"
                         :: "v"((u64)(fastH + di)), "v"(v) : "memory");

            if (t == TB - 1) {
                float2 hw = { h0, h1 };
                *(float2*)&out[64 + (size_t)(g*DB + sb)*HH + ug*64 + 2*sc] = hw;
            }
        }
        #pragma unroll
        for (int nt = 0; nt < 4; ++nt) xgc[nt] = xgn[nt];
        // no end-of-step barrier, no flag, no fence
    }

    // ---- final FC head: block ug==0 of each domain ----
    if (ug == 0) {
        size_t off = ((size_t)((TB - 1) & 1))*NB*NPAIR
                   + (size_t)(g*DB + sb)*NPAIR + sc*8;
        u64 pk[4];
        poll8_dual(fastH + off, slowH + off, (u32)TB, pk);
        float s = 0.f;
        const float4* wp = (const float4*)(Wfc + sc*16);
        #pragma unroll
        for (int k = 0; k < 4; ++k) {
            float4 w = wp[k];
            u64 p = pk[k];
            s += __uint_as_float((u32)( p        & 0xFFFFu) << 16) * w.x;
            s += __uint_as_float((u32)((p >> 16) & 0xFFFFu) << 16) * w.y;
            s += __uint_as_float((u32)((p >> 32) & 0xFFFFu) << 16) * w.z;
            s += __uint_as_float((u32)((p >> 48) & 0xFFFFu) << 16) * w.w;
        }
        __syncthreads();   // all act-phase P_lds reads done
        P_lds[sb][sc] = s;
        __syncthreads();
        if (tid < 8) {
            float acc = 0.f;
            #pragma unroll
            for (int q2 = 0; q2 < 32; ++q2) acc += P_lds[tid][q2];
            out[g*DB + tid] = sigf(acc + bfc[0]);
        }
    }
}

extern "C" void kernel_launch(void* const* d_in, const int* in_sizes, int n_in,
                              void* d_out, int out_size, void* d_ws, size_t ws_size,
                              hipStream_t stream) {
    (void)in_sizes; (void)n_in; (void)out_size; (void)ws_size;
    const int*   words = (const int*)d_in[0];
    const float* emb   = (const float*)d_in[1];
    const float* Wi    = (const float*)d_in[2];
    const float* bi    = (const float*)d_in[3];
    const float* Wh    = (const float*)d_in[4];
    const float* bh    = (const float*)d_in[5];
    const float* Wfc   = (const float*)d_in[6];
    const float* bfc   = (const float*)d_in[7];
    float* out = (float*)d_out;

    u64* fastH  = (u64*)d_ws;
    u64* slowH  = (u64*)((char*)d_ws + SLOWOFF);
    bf16_t* xgT = (bf16_t*)((char*)d_ws + XGOFF);

    // zero both tag buffers every launch (tag 0 matches no step)
    hipMemsetAsync(d_ws, 0, 2*SLOWOFF, stream);

    xg_prepass<<<dim3(256), dim3(256), 0, stream>>>(words, emb, Wi, bi, bh, xgT);
    lstm_main<<<dim3(ND*NBLK), dim3(NT), 0, stream>>>(Wh, Wfc, bfc, out,
                                                      fastH, slowH, (const u64*)xgT);
}

// Round 17
// 2017.318 us; speedup vs baseline: 3.2204x; 1.0667x over previous
//
#include <hip/hip_runtime.h>
#include <hip/hip_bf16.h>

// LSTM: B=64, T=512, V=32000, E=256, H=512, O=1
// R17 = R9 restored byte-for-byte (best measured: 2017us total).
// xg pre-pass (proven R7) + persistent recurrence with DUAL-PROTOCOL
// tagged exchange: every h-pair u64 (tag<<32 | 2xbf16) is stored BOTH
//   fast: global_store_dwordx2 ... sc0  (L2-visible if consumer on same XCD)
//   slow: agent-scope relaxed atomic    (always MALL-visible; proven R5-R7)
// Consumers hot-spin on the fast buffer, probing the slow buffer every 4th
// iteration. Liveness never depends on XCD placement; speed does.
// 8 domains (8 batches each) x 8 blocks (domain = blockIdx&7) x 256 threads.
#define TB 512
#define NB 64
#define EE 256
#define HH 512
#define ND 8           // sync domains
#define DB 8           // batches per domain
#define NBLK 8         // blocks per domain
#define NT 256         // threads per block (4 waves)
#define NCOLP 260      // P_lds padded row (floats)
#define NPAIR 256      // h pairs per batch
#define GCOLS 2048
#define SLOWOFF ((size_t)0x40000)  // slow buffer offset (fast at 0, 256KB each)
#define XGOFF   ((size_t)1 << 20)  // xg offset in d_ws

typedef __bf16 bf16_t;
typedef bf16_t bf16x8 __attribute__((ext_vector_type(8)));
typedef float  f32x4  __attribute__((ext_vector_type(4)));
typedef unsigned u32;
typedef unsigned long long u64;
typedef u32 u32x4 __attribute__((ext_vector_type(4)));

__device__ __forceinline__ float sigf(float x) { return 1.0f / (1.0f + __expf(-x)); }
__device__ __forceinline__ float tanhfast(float x) {
    float xc = fminf(fmaxf(x, -15.0f), 15.0f);
    float e  = __expf(2.0f * xc);
    return (e - 1.0f) / (e + 1.0f);
}
__device__ __forceinline__ u32 bfbits(float f) {
    bf16_t h = (bf16_t)f;
    return (u32)__builtin_bit_cast(unsigned short, h);
}
__device__ __forceinline__ bf16x8 cvt8(float4 a, float4 b) {
    bf16x8 v;
    v[0]=(bf16_t)a.x; v[1]=(bf16_t)a.y; v[2]=(bf16_t)a.z; v[3]=(bf16_t)a.w;
    v[4]=(bf16_t)b.x; v[5]=(bf16_t)b.y; v[6]=(bf16_t)b.z; v[7]=(bf16_t)b.w;
    return v;
}
__device__ __forceinline__ f32x4 cvtxg(u64 v) {
    f32x4 r;
    r[0] = __uint_as_float((u32)( v        & 0xFFFFu) << 16);
    r[1] = __uint_as_float((u32)((v >> 16) & 0xFFFFu) << 16);
    r[2] = __uint_as_float((u32)((v >> 32) & 0xFFFFu) << 16);
    r[3] = __uint_as_float((u32)((v >> 48) & 0xFFFFu) << 16);
    return r;
}

// Dual poll of 8 tagged u64s (64B): hot-spin sc0 (L2), slow probe every 4th.
// Tags ride in the data words, so acceptance is self-validating; the slow
// probe guarantees termination regardless of XCD placement.
__device__ __forceinline__ void poll8_dual(const u64* fsrc, const u64* ssrc,
                                           u32 tag, u64 (&pk)[4]) {
    u64 fa = (u64)fsrc;
    int it = 0;
    for (;;) {
        u32x4 q0, q1, q2, q3;
        asm volatile(
            "global_load_dwordx4 %0, %4, off sc0\n\t"
            "global_load_dwordx4 %1, %4, off offset:16 sc0\n\t"
            "global_load_dwordx4 %2, %4, off offset:32 sc0\n\t"
            "global_load_dwordx4 %3, %4, off offset:48 sc0\n\t"
            "s_waitcnt vmcnt(0)"
            : "=&v"(q0), "=&v"(q1), "=&v"(q2), "=&v"(q3)
            : "v"(fa)
            : "memory");
        if (q0[1]==tag && q0[3]==tag && q1[1]==tag && q1[3]==tag &&
            q2[1]==tag && q2[3]==tag && q3[1]==tag && q3[3]==tag) {
            pk[0] = (u64)q0[0] | ((u64)q0[2] << 32);
            pk[1] = (u64)q1[0] | ((u64)q1[2] << 32);
            pk[2] = (u64)q2[0] | ((u64)q2[2] << 32);
            pk[3] = (u64)q3[0] | ((u64)q3[2] << 32);
            return;
        }
        if (((++it) & 3) == 0) {
            u64 hv[8];
            #pragma unroll
            for (int j = 0; j < 8; ++j)
                hv[j] = __hip_atomic_load(ssrc + j, __ATOMIC_RELAXED, __HIP_MEMORY_SCOPE_AGENT);
            bool ok = true;
            #pragma unroll
            for (int j = 0; j < 8; ++j) ok &= ((u32)(hv[j] >> 32) == tag);
            if (ok) {
                #pragma unroll
                for (int k = 0; k < 4; ++k)
                    pk[k] = (u64)(u32)hv[2*k] | ((u64)(u32)hv[2*k + 1] << 32);
                return;
            }
        }
    }
}

// ---------------- Phase 1: xg pre-pass GEMM (proven R7, verbatim) ----------------
__global__ __launch_bounds__(256, 1)
void xg_prepass(const int* __restrict__ words, const float* __restrict__ emb,
                const float* __restrict__ Wi, const float* __restrict__ bi,
                const float* __restrict__ bh, bf16_t* __restrict__ xgT)
{
    const int tid = threadIdx.x, lane = tid & 63, wv = tid >> 6;
    const int kgrp = lane >> 4, cl = lane & 15;
    const int cc = blockIdx.x & 7, tc = blockIdx.x >> 3;

    __shared__ __align__(16) bf16_t x_s[64][EE];

    bf16x8 wf[8][4];
    float  bv[4];
    #pragma unroll
    for (int nt = 0; nt < 4; ++nt) {
        int col = cc*256 + wv*64 + nt*16 + cl;
        int wrow = (col & 3)*HH + (col >> 2);
        const float* wr = Wi + (size_t)wrow*EE;
        #pragma unroll
        for (int kt = 0; kt < 8; ++kt) {
            const float4* p = (const float4*)(wr + kt*32 + kgrp*8);
            wf[kt][nt] = cvt8(p[0], p[1]);
        }
        bv[nt] = bi[wrow] + bh[wrow];
    }

    const int r0 = tid >> 2, q = tid & 3;
    const int swz = (r0 & 7) << 3;
    u64* dst = (u64*)xgT;

    for (int it = 0; it < 16; ++it) {
        int t = tc*16 + it;
        {
            int wd = words[r0*TB + t];
            const float4* p = (const float4*)(emb + (size_t)wd*EE + q*64);
            #pragma unroll
            for (int o = 0; o < 8; ++o) {
                float4 a = p[2*o], b2 = p[2*o + 1];
                *(bf16x8*)&x_s[r0][(q*64 + o*8) ^ swz] = cvt8(a, b2);
            }
        }
        __syncthreads();

        f32x4 acc[4][4];
        #pragma unroll
        for (int rt = 0; rt < 4; ++rt)
            #pragma unroll
            for (int nt = 0; nt < 4; ++nt)
                acc[rt][nt] = (f32x4){ bv[nt], bv[nt], bv[nt], bv[nt] };
        #pragma unroll
        for (int kt = 0; kt < 8; ++kt) {
            #pragma unroll
            for (int rt = 0; rt < 4; ++rt) {
                bf16x8 a = *(const bf16x8*)&x_s[rt*16 + cl][(kt*32 + kgrp*8) ^ ((cl & 7) << 3)];
                #pragma unroll
                for (int nt = 0; nt < 4; ++nt)
                    acc[rt][nt] = __builtin_amdgcn_mfma_f32_16x16x32_bf16(a, wf[kt][nt], acc[rt][nt], 0, 0, 0);
            }
        }
        #pragma unroll
        for (int nt = 0; nt < 4; ++nt) {
            int col = cc*256 + wv*64 + nt*16 + cl;
            #pragma unroll
            for (int rt = 0; rt < 4; ++rt) {
                f32x4 v = acc[rt][nt];
                u64 pkk =  (u64)(bfbits(v[0]))
                        | ((u64)(bfbits(v[1])) << 16)
                        | ((u64)(bfbits(v[2])) << 32)
                        | ((u64)(bfbits(v[3])) << 48);
                dst[(size_t)(t*GCOLS + col)*16 + rt*4 + kgrp] = pkk;
            }
        }
        __syncthreads();
    }
}

// ---------------- Phase 2: persistent recurrence, dual-protocol exchange ----------------
__global__ __launch_bounds__(NT, 1)
void lstm_main(const float* __restrict__ Wh,
               const float* __restrict__ Wfc,
               const float* __restrict__ bfc,
               float* __restrict__ out,        // [64] head + [64*512] h (fp32)
               u64* __restrict__ fastH,        // [2][NB][NPAIR] tagged pairs (sc0)
               u64* __restrict__ slowH,        // [2][NB][NPAIR] tagged pairs (agent)
               const u64* __restrict__ xg64)   // xg[t][col][batchquad]
{
    const int tid  = threadIdx.x;
    const int lane = tid & 63;
    const int wv   = tid >> 6;        // 0..3
    const int g    = blockIdx.x & 7;  // domain (-> one XCD under round-robin)
    const int ug   = blockIdx.x >> 3; // unit group 0..7 (64 units each)
    const int kgrp = lane >> 4;
    const int cl   = lane & 15;

    __shared__ __align__(16) bf16_t h_lds[16][HH];    // rows 8..15 stay zero
    __shared__ __align__(16) float  P_lds[16][NCOLP];

    // zero h_lds (h_{-1}=0)
    for (int i = tid; i < 16*HH/2; i += NT) ((u32*)h_lds)[i] = 0u;

    // ---- Wh fragments: 4 n-tiles per wave (256 local cols per block) ----
    bf16x8 whf[16][4];
    #pragma unroll
    for (int nt = 0; nt < 4; ++nt) {
        int gc = ug*256 + wv*64 + nt*16 + cl;       // global gate-col
        int wrow = (gc & 3)*HH + (gc >> 2);
        const float* wr = Wh + (size_t)wrow*HH;
        #pragma unroll
        for (int kt = 0; kt < 16; ++kt) {
            const float4* p = (const float4*)(wr + kt*32 + kgrp*8);
            whf[kt][nt] = cvt8(p[0], p[1]);
        }
    }

    // thread roles for poll/act: batch sb (0..7), chunk sc (0..31)
    const int sb = tid >> 5, sc = tid & 31;
    const int swz = sb << 3;

    // xg addressing: quad m covers batches 4m..4m+3; local rows kgrp*4+r
    const int m = 2*g + (kgrp & 1);
    int gc[4];
    #pragma unroll
    for (int nt = 0; nt < 4; ++nt) gc[nt] = ug*256 + wv*64 + nt*16 + cl;

    u64 xgc[4], xgn[4];
    #pragma unroll
    for (int nt = 0; nt < 4; ++nt) xgc[nt] = xg64[(size_t)gc[nt]*16 + m];

    float c0 = 0.f, c1 = 0.f;
    __syncthreads();

    for (int t = 0; t < TB; ++t) {
        // ---- poll tagged h_{t-1} (8 pairs from one producer), stage to LDS ----
        if (t > 0) {
            size_t off = ((size_t)((t & 1) ^ 1))*NB*NPAIR
                       + (size_t)(g*DB + sb)*NPAIR + sc*8;
            u64 pk[4];
            poll8_dual(fastH + off, slowH + off, (u32)t, pk);
            #pragma unroll
            for (int k = 0; k < 4; ++k) {
                int e = sc*16 + 4*k;
                int phys = ((e & ~7) ^ swz) | (e & 7);
                *(u64*)&h_lds[sb][phys] = pk[k];
            }
        }

        // ---- prefetch xg(t+1): sequential, one full step of slack ----
        if (t + 1 < TB) {
            #pragma unroll
            for (int nt = 0; nt < 4; ++nt)
                xgn[nt] = xg64[(size_t)((t + 1)*GCOLS + gc[nt])*16 + m];
        }
        __syncthreads();   // B1: h_lds visible

        // ---- recurrent MFMAs, acc seeded from xg (bias pre-folded) ----
        f32x4 acc[4];
        #pragma unroll
        for (int nt = 0; nt < 4; ++nt) acc[nt] = cvtxg(xgc[nt]);
        if (t > 0) {
            #pragma unroll
            for (int kt = 0; kt < 16; ++kt) {
                bf16x8 a = *(const bf16x8*)&h_lds[cl][(kt*32 + kgrp*8) ^ ((cl & 7) << 3)];
                #pragma unroll
                for (int nt = 0; nt < 4; ++nt)
                    acc[nt] = __builtin_amdgcn_mfma_f32_16x16x32_bf16(a, whf[kt][nt], acc[nt], 0, 0, 0);
            }
        }

        // ---- preactivations: row = kgrp*4+r (local batch), col = local gate-col ----
        #pragma unroll
        for (int nt = 0; nt < 4; ++nt)
            #pragma unroll
            for (int r = 0; r < 4; ++r)
                P_lds[kgrp*4 + r][wv*64 + nt*16 + cl] = acc[nt][r];
        __syncthreads();   // B2: P visible

        // ---- activations: thread owns (batch sb, units 2*sc, 2*sc+1) ----
        {
            float4 g0 = *(const float4*)&P_lds[sb][sc*8];
            float4 g1 = *(const float4*)&P_lds[sb][sc*8 + 4];
            float r0 = sigf(g0.x), f0 = sigf(g0.y), z0 = tanhfast(g0.z), o0 = sigf(g0.w);
            float r1 = sigf(g1.x), f1 = sigf(g1.y), z1 = tanhfast(g1.z), o1 = sigf(g1.w);
            c0 = f0*c0 + r0*z0;
            c1 = f1*c1 + r1*z1;
            float h0 = o0*tanhfast(c0);
            float h1 = o1*tanhfast(c1);
            if (t == TB - 1) {
                float2 hw = { h0, h1 };
                *(float2*)&out[64 + (size_t)(g*DB + sb)*HH + ug*64 + 2*sc] = hw;
            }
            // dual publish: tagged u64, fast (sc0) + slow (agent atomic)
            u64 v = (((u64)(u32)(t + 1)) << 32)
                  | (u64)(bfbits(h0) | (bfbits(h1) << 16));
            size_t di = ((size_t)(t & 1))*NB*NPAIR
                      + (size_t)(g*DB + sb)*NPAIR + ug*32 + sc;
            asm volatile("global_store_dwordx2 %0, %1, off sc0"
                         :: "v"((u64)(fastH + di)), "v"(v) : "memory");
            __hip_atomic_store(slowH + di, v, __ATOMIC_RELAXED, __HIP_MEMORY_SCOPE_AGENT);
        }
        #pragma unroll
        for (int nt = 0; nt < 4; ++nt) xgc[nt] = xgn[nt];
        // no end-of-step barrier, no flag, no fence
    }

    // ---- final FC head: block ug==0 of each domain ----
    if (ug == 0) {
        size_t off = ((size_t)((TB - 1) & 1))*NB*NPAIR
                   + (size_t)(g*DB + sb)*NPAIR + sc*8;
        u64 pk[4];
        poll8_dual(fastH + off, slowH + off, (u32)TB, pk);
        float s = 0.f;
        const float4* wp = (const float4*)(Wfc + sc*16);
        #pragma unroll
        for (int k = 0; k < 4; ++k) {
            float4 w = wp[k];
            u64 p = pk[k];
            s += __uint_as_float((u32)( p        & 0xFFFFu) << 16) * w.x;
            s += __uint_as_float((u32)((p >> 16) & 0xFFFFu) << 16) * w.y;
            s += __uint_as_float((u32)((p >> 32) & 0xFFFFu) << 16) * w.z;
            s += __uint_as_float((u32)((p >> 48) & 0xFFFFu) << 16) * w.w;
        }
        __syncthreads();   // all act-phase P_lds reads done
        P_lds[sb][sc] = s;
        __syncthreads();
        if (tid < 8) {
            float acc = 0.f;
            #pragma unroll
            for (int q2 = 0; q2 < 32; ++q2) acc += P_lds[tid][q2];
            out[g*DB + tid] = sigf(acc + bfc[0]);
        }
    }
}

extern "C" void kernel_launch(void* const* d_in, const int* in_sizes, int n_in,
                              void* d_out, int out_size, void* d_ws, size_t ws_size,
                              hipStream_t stream) {
    (void)in_sizes; (void)n_in; (void)out_size; (void)ws_size;
    const int*   words = (const int*)d_in[0];
    const float* emb   = (const float*)d_in[1];
    const float* Wi    = (const float*)d_in[2];
    const float* bi    = (const float*)d_in[3];
    const float* Wh    = (const float*)d_in[4];
    const float* bh    = (const float*)d_in[5];
    const float* Wfc   = (const float*)d_in[6];
    const float* bfc   = (const float*)d_in[7];
    float* out = (float*)d_out;

    u64* fastH  = (u64*)d_ws;
    u64* slowH  = (u64*)((char*)d_ws + SLOWOFF);
    bf16_t* xgT = (bf16_t*)((char*)d_ws + XGOFF);

    // zero both tag buffers every launch (tag 0 matches no step)
    hipMemsetAsync(d_ws, 0, 2*SLOWOFF, stream);

    xg_prepass<<<dim3(256), dim3(256), 0, stream>>>(words, emb, Wi, bi, bh, xgT);
    lstm_main<<<dim3(ND*NBLK), dim3(NT), 0, stream>>>(Wh, Wfc, bfc, out,
                                                      fastH, slowH, (const u64*)xgT);
}